// Round 1
// baseline (213.718 us; speedup 1.0000x reference)
//
#include <hip/hip_runtime.h>
#include <hip/hip_bf16.h>
#include <stdint.h>

typedef __bf16 bf16;
typedef __bf16 bf16x2 __attribute__((ext_vector_type(2)));
typedef __bf16 bf16x4 __attribute__((ext_vector_type(4)));
typedef __bf16 bf16x8 __attribute__((ext_vector_type(8)));
typedef float f32x4 __attribute__((ext_vector_type(4)));
typedef float f32x16 __attribute__((ext_vector_type(16)));

#define D_MODEL 768
#define NUM_HEADS 48
#define HEAD_CH 16
#define INNER 2304
#define BATCH 2
#define SEQLEN 2048
#define M_ROWS (BATCH * SEQLEN)
#define EPSF 1e-6f
// h-table: T[nh][C+4][reg] bf16, C = (l0-mc) + l31 - 4*hi in [-4, 2047].
// reg order matches 32x32 MFMA D layout: value = h[C - 8*(reg>>2) - (reg&3)],
// zero when index < 0 (this encodes the causal mask of the diagonal tile).
#define HT_ROWS 2052
#define HGEN_N (NUM_HEADS * HT_ROWS * 4)  // bf16x4 elements

// async global->LDS, 16B per lane. LDS dest must be wave-uniform base + lane*16.
__device__ inline void gload_lds16(const void* g, void* l) {
  __builtin_amdgcn_global_load_lds((__attribute__((address_space(1))) void*)(g),
                                   (__attribute__((address_space(3))) void*)(l),
                                   16, 0, 0);
}

// ---------------------------------------------------------------------------
// fused dual f32 -> bf16 convert (two independent tensors, one launch)
// ---------------------------------------------------------------------------
__global__ __launch_bounds__(256) void cvt2_f32_bf16(
    const float* __restrict__ a, bf16* __restrict__ da, int na4,
    const float* __restrict__ b, bf16* __restrict__ db, int nb4) {
  int j = blockIdx.x * 256 + threadIdx.x;
  const float* s;
  bf16* d;
  if (j < na4) {
    s = a; d = da;
  } else {
    j -= na4;
    if (j >= nb4) return;
    s = b; d = db;
  }
  const float4 v = ((const float4*)s)[j];
  bf16x4 o;
  o[0] = (bf16)v.x; o[1] = (bf16)v.y; o[2] = (bf16)v.z; o[3] = (bf16)v.w;
  ((bf16x4*)d)[j] = o;
}

// ---------------------------------------------------------------------------
// w_out f32->bf16 convert + h-table generation (one launch, runs after conv
// so the dead u-region tail can hold the table)
// ---------------------------------------------------------------------------
__global__ __launch_bounds__(256) void cvt_wout_hgen(
    const float* __restrict__ wout, bf16* __restrict__ wout16, int n4,
    const float* __restrict__ hb, bf16* __restrict__ ht) {
  int j = blockIdx.x * 256 + threadIdx.x;
  if (j < n4) {
    const float4 v = ((const float4*)wout)[j];
    bf16x4 o;
    o[0] = (bf16)v.x; o[1] = (bf16)v.y; o[2] = (bf16)v.z; o[3] = (bf16)v.w;
    ((bf16x4*)wout16)[j] = o;
    return;
  }
  j -= n4;
  if (j >= HGEN_N) return;
  const int nh = j / (HT_ROWS * 4);
  const int rem = j - nh * (HT_ROWS * 4);
  const int Cp = rem >> 2, rb = rem & 3;  // row Cp, regs rb*4..rb*4+3
  const float* hrow = hb + nh * SEQLEN;
  const int base = Cp - 4 - 8 * rb;  // idx for rr=0
  bf16x4 o;
#pragma unroll
  for (int rr = 0; rr < 4; ++rr) {
    const int idx = base - rr;
    o[rr] = (bf16)((idx >= 0) ? hrow[idx] : 0.f);
  }
  ((bf16x4*)ht)[j] = o;
}

// ---------------------------------------------------------------------------
// GEMM: C[m,n] = sum_k A[m,k]*W[n,k] + bias[n] (+ skip[m,n]); A (M,K), W (N,K)
// m97 pattern, TM x TN tile, BK in {32,64}. BK=64 stores two [kk0][row][32]
// sub-blocks -> DMA contiguity and 32-col fragment addressing preserved,
// barrier count halves (12 iters at K=768).
// ---------------------------------------------------------------------------
template <int TM, int TN, int BK, int NCOLS, bool ADD_SKIP, typename CT>
__global__ __launch_bounds__(256) void gemm_bt(
    const bf16* __restrict__ A, const bf16* __restrict__ W,
    const float* __restrict__ bias, const float* __restrict__ skip,
    CT* __restrict__ C, int K) {
  constexpr int MI = TM / 32;  // m-frags per wave
  constexpr int NI = TN / 32;  // n-frags per wave
  constexpr int KK = BK / 32;  // k sub-blocks
  __shared__ __align__(16) bf16 As[TM * BK];
  __shared__ __align__(16) bf16 Bs[TN * BK];
  const int t = threadIdx.x;
  const int lane = t & 63, w = t >> 6;
  const int wm = (w >> 1) * (TM / 2), wn = (w & 1) * (TN / 2);
  const int row16 = lane & 15, quad = lane >> 4;
  const int m0 = blockIdx.x * TM, n0 = blockIdx.y * TN;

  f32x4 zero4 = {0.f, 0.f, 0.f, 0.f};
  f32x4 acc[MI][NI];
#pragma unroll
  for (int mi = 0; mi < MI; ++mi)
#pragma unroll
    for (int ni = 0; ni < NI; ++ni) acc[mi][ni] = zero4;

  const int arow = t >> 2;        // 0..63
  const int acol = (t & 3) * 8;   // 0..24
  const bf16* Ab = A + (size_t)m0 * K;
  const bf16* Wb = W + (size_t)n0 * K;

  for (int kt = 0; kt < K; kt += BK) {
#pragma unroll
    for (int kk0 = 0; kk0 < KK; ++kk0) {
#pragma unroll
      for (int rh = 0; rh < TM / 64; ++rh)
        gload_lds16(Ab + (size_t)(rh * 64 + arow) * K + kt + kk0 * 32 + acol,
                    As + kk0 * (TM * 32) + rh * 2048 + t * 8);
#pragma unroll
      for (int rh = 0; rh < TN / 64; ++rh)
        gload_lds16(Wb + (size_t)(rh * 64 + arow) * K + kt + kk0 * 32 + acol,
                    Bs + kk0 * (TN * 32) + rh * 2048 + t * 8);
    }
    __syncthreads();

    bf16x8 af[MI][KK], wf[NI][KK];
#pragma unroll
    for (int kk0 = 0; kk0 < KK; ++kk0) {
#pragma unroll
      for (int mi = 0; mi < MI; ++mi)
        af[mi][kk0] = *(const bf16x8*)&As[kk0 * (TM * 32) +
                                          (wm + mi * 16 + row16) * 32 +
                                          quad * 8];
#pragma unroll
      for (int ni = 0; ni < NI; ++ni)
        wf[ni][kk0] = *(const bf16x8*)&Bs[kk0 * (TN * 32) +
                                          (wn + ni * 16 + row16) * 32 +
                                          quad * 8];
    }
#pragma unroll
    for (int kk0 = 0; kk0 < KK; ++kk0)
#pragma unroll
      for (int mi = 0; mi < MI; ++mi)
#pragma unroll
        for (int ni = 0; ni < NI; ++ni)
          acc[mi][ni] = __builtin_amdgcn_mfma_f32_16x16x32_bf16(
              af[mi][kk0], wf[ni][kk0], acc[mi][ni], 0, 0, 0);
    __syncthreads();
  }

#pragma unroll
  for (int mi = 0; mi < MI; ++mi) {
#pragma unroll
    for (int ni = 0; ni < NI; ++ni) {
      const int col = n0 + wn + ni * 16 + row16;
      const float bv = bias[col];
#pragma unroll
      for (int r = 0; r < 4; ++r) {
        const int row = m0 + wm + mi * 16 + quad * 4 + r;
        float v = acc[mi][ni][r] + bv;
        if (ADD_SKIP) v += skip[(size_t)row * NCOLS + col];
        C[(size_t)row * NCOLS + col] = (CT)v;
      }
    }
  }
}

// ---------------------------------------------------------------------------
// Q+K+V causal width-3 conv from u:
//   ch 0..15  -> Q (B,N,L,16);  16..31 -> K (B,N,L,16);  32..47 -> V (B,N,16,L)
// ---------------------------------------------------------------------------
__global__ __launch_bounds__(256) void conv_qkv(
    const bf16* __restrict__ u, const float* __restrict__ w_sf,
    const float* __restrict__ b_sf, bf16* __restrict__ qq,
    bf16* __restrict__ kk, bf16* __restrict__ vv) {
  const int nh = blockIdx.x, b = blockIdx.y, lc = blockIdx.z;
  const int l0 = lc * 128;
  __shared__ __align__(8) bf16 ut[130 * 48];
  const int t = threadIdx.x;
  for (int i = t; i < 130 * 12; i += 256) {
    const int lr = i / 12, qd = i % 12;
    const int l = l0 - 2 + lr;
    uint2 val;
    val.x = 0u; val.y = 0u;
    if (l >= 0)
      val = *(const uint2*)&u[(size_t)(b * SEQLEN + l) * INNER + nh * 48 + qd * 4];
    *(uint2*)&ut[lr * 48 + qd * 4] = val;
  }
  __syncthreads();
  const size_t bn = (size_t)(b * NUM_HEADS + nh);
#pragma unroll
  for (int s = 0; s < 2; ++s) {
    bf16* dst = (s == 0) ? qq : kk;
    const int cb = s * 16;
    for (int i = t; i < 128 * 16; i += 256) {
      const int c = i & 15, lr = i >> 4;
      const int e = nh * 48 + cb + c;
      const float val = w_sf[e * 3 + 0] * (float)ut[lr * 48 + cb + c] +
                        w_sf[e * 3 + 1] * (float)ut[(lr + 1) * 48 + cb + c] +
                        w_sf[e * 3 + 2] * (float)ut[(lr + 2) * 48 + cb + c] +
                        b_sf[e];
      dst[(bn * SEQLEN + l0 + lr) * 16 + c] = (bf16)val;
    }
  }
  for (int i = t; i < 128 * 16; i += 256) {
    const int lr = i & 127, c = i >> 7;
    const int e = nh * 48 + 32 + c;
    const float val = w_sf[e * 3 + 0] * (float)ut[lr * 48 + 32 + c] +
                      w_sf[e * 3 + 1] * (float)ut[(lr + 1) * 48 + 32 + c] +
                      w_sf[e * 3 + 2] * (float)ut[(lr + 2) * 48 + 32 + c] +
                      b_sf[e];
    vv[(bn * 16 + c) * SEQLEN + l0 + lr] = (bf16)val;
  }
}

// ---------------------------------------------------------------------------
// Causal h-weighted attention v11: LDS-free main loop.
// Block z owns paired tiles (z, 63-z); 65 combined KV chunks dealt round-robin
// to the 4 waves. Per chunk:
//   S = mfma_32x32x16(K, Q)        (lane: col l=lane&31, 16 m-regs)
//   P = S * h[l-m] via bf16 h-table in MFMA reg order (2x16B global, L2-hot)
//   cvt_pk pairs -> 8 dwords; 4x v_permlane32_swap -> B-frag (k = 8*hi+jj)
//   O^T[j,l] += mfma_32x32x16(Vfrag, Pfrag) x2 (m halves); j>=16 cols wasted.
// Replaces ~150 LDS-pipe cyc/iter (unaligned per-elem h reads + S transpose
// round-trip + 5.2M bank conflicts) with 5 vector loads + 4 permlanes.
// ---------------------------------------------------------------------------
__global__ __launch_bounds__(256) void attn_kernel(
    const bf16* __restrict__ qq, const bf16* __restrict__ kk,
    const bf16* __restrict__ vv, const bf16* __restrict__ ht,
    bf16* __restrict__ y) {
  const int nh = blockIdx.x, b = blockIdx.y;
  const int qa = blockIdx.z, qb = 63 - qa;  // paired tiles
  const int l0a = qa * 32, l0b = qb * 32;
  __shared__ __align__(16) float red[4 * 32 * 17];  // stride 17: conflict-free
  const int t = threadIdx.x;
  const int w = t >> 6, lane = t & 63;
  const int l31 = lane & 31, hi = lane >> 5;
  const size_t bn = (size_t)(b * NUM_HEADS + nh);
  const bf16* qp = qq + bn * SEQLEN * 16;
  const bf16* kb = kk + bn * SEQLEN * 16;
  const bf16* vrp = vv + (bn * 16 + (lane & 15)) * SEQLEN;
  // row for chunk mc of tile l0: (l0-mc) + l31 - 4*hi + 4
  const bf16* hbase =
      ht + ((size_t)nh * HT_ROWS + (size_t)(l31 - 4 * hi + 4)) * 16;

  bf16x8 zf;
#pragma unroll
  for (int j = 0; j < 8; ++j) zf[j] = (bf16)0.f;
  f32x16 zacc;
#pragma unroll
  for (int j = 0; j < 16; ++j) zacc[j] = 0.f;

  const bf16x8 qfa = *(const bf16x8*)&qp[(l0a + l31) * 16 + hi * 8];
  const bf16x8 qfb = *(const bf16x8*)&qp[(l0b + l31) * 16 + hi * 8];

  auto run_pass = [&](const bf16x8 qf, const int l0, const int mc0,
                      f32x16& acc) {
    int mc = mc0;
    bf16x8 kf = zf, vf0 = zf, vf1 = zf, hf0 = zf, hf1 = zf;
    if (mc <= l0) {
      kf = *(const bf16x8*)&kb[(mc + l31) * 16 + hi * 8];
      vf0 = *(const bf16x8*)&vrp[mc + 8 * hi];
      vf1 = *(const bf16x8*)&vrp[mc + 16 + 8 * hi];
      const bf16* hp = hbase + (size_t)(l0 - mc) * 16;
      hf0 = *(const bf16x8*)hp;
      hf1 = *(const bf16x8*)(hp + 8);
    }
    for (; mc <= l0; mc += 128) {
      const int mn = mc + 128;
      bf16x8 kf2 = zf, vf02 = zf, vf12 = zf, hf02 = zf, hf12 = zf;
      if (mn <= l0) {  // prefetch next chunk
        kf2 = *(const bf16x8*)&kb[(mn + l31) * 16 + hi * 8];
        vf02 = *(const bf16x8*)&vrp[mn + 8 * hi];
        vf12 = *(const bf16x8*)&vrp[mn + 16 + 8 * hi];
        const bf16* hp = hbase + (size_t)(l0 - mn) * 16;
        hf02 = *(const bf16x8*)hp;
        hf12 = *(const bf16x8*)(hp + 8);
      }
      // S^T: lane holds col l=l31; reg 4g+r -> m = 4*hi + 8*g + r
      const f32x16 s =
          __builtin_amdgcn_mfma_f32_32x32x16_bf16(kf, qf, zacc, 0, 0, 0);
      // h-weight + pack to bf16 dword pairs (m, m+1) per dword
      uint32_t dw[4][2];
#pragma unroll
      for (int g = 0; g < 4; ++g) {
#pragma unroll
        for (int u2 = 0; u2 < 2; ++u2) {
          const int r0 = 4 * g + 2 * u2;
          const float h0 = (float)((g < 2) ? hf0[r0 & 7] : hf1[r0 & 7]);
          const float h1 =
              (float)((g < 2) ? hf0[(r0 + 1) & 7] : hf1[(r0 + 1) & 7]);
          bf16x2 tt;
          tt[0] = (bf16)(s[r0] * h0);
          tt[1] = (bf16)(s[r0 + 1] * h1);
          union { bf16x2 h; uint32_t u; } cv;
          cv.h = tt;
          dw[g][u2] = cv.u;
        }
      }
      // permlane32_swap: out[0] = {a.lo, b.lo}, out[1] = {a.hi, b.hi}
      // -> B-frag dwords w(jj-pair) with k = 8*hi + jj
      auto p0 = __builtin_amdgcn_permlane32_swap(dw[0][0], dw[1][0], false, false);
      auto p1 = __builtin_amdgcn_permlane32_swap(dw[0][1], dw[1][1], false, false);
      auto p2 = __builtin_amdgcn_permlane32_swap(dw[2][0], dw[3][0], false, false);
      auto p3 = __builtin_amdgcn_permlane32_swap(dw[2][1], dw[3][1], false, false);
      union U8 { uint32_t u[4]; bf16x8 f; } f1, f2;
      f1.u[0] = p0[0]; f1.u[1] = p1[0]; f1.u[2] = p0[1]; f1.u[3] = p1[1];
      f2.u[0] = p2[0]; f2.u[1] = p3[0]; f2.u[2] = p2[1]; f2.u[3] = p3[1];
      // O^T[j,l]: A = V (rows j, dup for lane>=16), B = P; m halves 0..15,16..31
      acc = __builtin_amdgcn_mfma_f32_32x32x16_bf16(vf0, f1.f, acc, 0, 0, 0);
      acc = __builtin_amdgcn_mfma_f32_32x32x16_bf16(vf1, f2.f, acc, 0, 0, 0);
      kf = kf2; vf0 = vf02; vf1 = vf12; hf0 = hf02; hf1 = hf12;
    }
  };

  f32x16 acca = zacc, accb = zacc;
  run_pass(qfa, l0a, w * 32, acca);
  const int j0 = ((w - qa - 1) % 4 + 4) % 4;
  run_pass(qfb, l0b, j0 * 32, accb);

  // epilogue: acc regs 0..7 valid: j = 4*hi + 8*g + r (g<2), col l = l31
  float* ob = &red[w * 544];
#pragma unroll
  for (int phase = 0; phase < 2; ++phase) {
    const f32x16& A = phase ? accb : acca;
    const int lt = phase ? l0b : l0a;
    if (phase) __syncthreads();  // previous reads done before overwrite
#pragma unroll
    for (int g = 0; g < 2; ++g)
#pragma unroll
      for (int r = 0; r < 4; ++r)
        ob[l31 * 17 + 4 * hi + 8 * g + r] = A[4 * g + r];
    __syncthreads();
    for (int i = t; i < 512; i += 256) {
      const int l = i >> 4, jj = i & 15;
      const int o = l * 17 + jj;
      const float sum = red[o] + red[544 + o] + red[1088 + o] + red[1632 + o];
      y[((size_t)(b * SEQLEN + lt + l) * NUM_HEADS + nh) * 16 + jj] = (bf16)sum;
    }
  }
}

// ---------------------------------------------------------------------------
// RMSNorm over D=768 per row: y bf16 in, yn bf16 out, * norm_w (f32)
// ---------------------------------------------------------------------------
__global__ __launch_bounds__(256) void rmsnorm_k(
    const bf16* __restrict__ y, const float* __restrict__ nw,
    bf16* __restrict__ yn) {
  const int row = blockIdx.x;
  const int t = threadIdx.x;
  const bf16* yr = y + (size_t)row * D_MODEL;
  const float v0 = (float)yr[t];
  const float v1 = (float)yr[t + 256];
  const float v2 = (float)yr[t + 512];
  float ss = v0 * v0 + v1 * v1 + v2 * v2;
#pragma unroll
  for (int off = 32; off >= 1; off >>= 1) ss += __shfl_down(ss, off, 64);
  __shared__ float red[4];
  if ((t & 63) == 0) red[t >> 6] = ss;
  __syncthreads();
  const float tot = red[0] + red[1] + red[2] + red[3];
  const float r = rsqrtf(tot * (1.f / 768.f) + EPSF);
  bf16* yo = yn + (size_t)row * D_MODEL;
  yo[t] = (bf16)(v0 * r * nw[t]);
  yo[t + 256] = (bf16)(v1 * r * nw[t + 256]);
  yo[t + 512] = (bf16)(v2 * r * nw[t + 512]);
}

// ---------------------------------------------------------------------------
extern "C" void kernel_launch(void* const* d_in, const int* in_sizes, int n_in,
                              void* d_out, int out_size, void* d_ws,
                              size_t ws_size, hipStream_t stream) {
  const float* inputs = (const float*)d_in[0];
  const float* w_in = (const float*)d_in[1];
  const float* b_in = (const float*)d_in[2];
  const float* w_sf = (const float*)d_in[3];
  const float* b_sf = (const float*)d_in[4];
  const float* hb = (const float*)d_in[5];
  const float* norm_w = (const float*)d_in[6];
  const float* w_out = (const float*)d_in[7];
  const float* b_out = (const float*)d_in[8];

  // ws plan (37.8 MB), region lifetimes:
  //   u   18.9 MB : GEMM1 out -> dead after conv_qkv; tail reused for
  //                 wout16 (+0, 1.2MB), yn (+2MB, 6MB), y16 (+8MB, 6MB),
  //                 ht (+14MB, 3.0MB h-table, written by cvt_wout_hgen)
  //   v    6.3 MB : V
  //   A    6.3 MB : in16 (GEMM1 A) -> k16 (attn) -> dead
  //   B    6.3 MB : win16 (GEMM1 W, 3.5MB) -> q16 (attn)
  char* ws = (char*)d_ws;
  const size_t U_B = (size_t)M_ROWS * INNER * 2;
  const size_t V_B = (size_t)BATCH * NUM_HEADS * HEAD_CH * SEQLEN * 2;
  const size_t SLOT_B = (size_t)M_ROWS * D_MODEL * 2;
  bf16* u = (bf16*)(ws);
  bf16* wout16 = (bf16*)(ws);                    // u region, after conv
  bf16* yn = (bf16*)(ws + (2 << 20));            // u region +2MB
  bf16* y16 = (bf16*)(ws + (8 << 20));           // u region +8MB (..14MB)
  bf16* ht = (bf16*)(ws + (14 << 20));           // u region +14MB (..17.1MB)
  bf16* v = (bf16*)(ws + U_B);
  bf16* in16 = (bf16*)(ws + U_B + V_B);          // A
  bf16* k16 = in16;                              // A after GEMM1
  bf16* win16 = (bf16*)(ws + U_B + V_B + SLOT_B);// B
  bf16* q16 = win16;                             // B after GEMM1
  float* out = (float*)d_out;

  const int n4_in = M_ROWS * D_MODEL / 4;
  const int n4_win = INNER * D_MODEL / 4;
  const int n4_wout = D_MODEL * D_MODEL / 4;
  hipLaunchKernelGGL(cvt2_f32_bf16, dim3((n4_in + n4_win + 255) / 256),
                     dim3(256), 0, stream, inputs, in16, n4_in, w_in, win16,
                     n4_win);

  hipLaunchKernelGGL((gemm_bt<64, 128, 64, INNER, false, bf16>), dim3(64, 18),
                     dim3(256), 0, stream, in16, win16, b_in,
                     (const float*)nullptr, u, 768);
  hipLaunchKernelGGL(conv_qkv, dim3(48, 2, 16), dim3(256), 0, stream, u, w_sf,
                     b_sf, q16, k16, v);
  // u dead now: stage w_out + build the h-table in its head/tail
  hipLaunchKernelGGL(cvt_wout_hgen, dim3((n4_wout + HGEN_N + 255) / 256),
                     dim3(256), 0, stream, w_out, wout16, n4_wout, hb, ht);
  hipLaunchKernelGGL(attn_kernel, dim3(48, 2, 32), dim3(256), 0, stream, q16,
                     k16, v, ht, y16);
  hipLaunchKernelGGL(rmsnorm_k, dim3(M_ROWS), dim3(256), 0, stream, y16,
                     norm_w, yn);
  hipLaunchKernelGGL((gemm_bt<64, 64, 64, D_MODEL, true, float>), dim3(64, 12),
                     dim3(256), 0, stream, yn, wout16, b_out, inputs, out,
                     768);
}

// Round 3
// 195.931 us; speedup vs baseline: 1.0908x; 1.0908x over previous
//
#include <hip/hip_runtime.h>
#include <hip/hip_bf16.h>
#include <stdint.h>

typedef __bf16 bf16;
typedef __bf16 bf16x4 __attribute__((ext_vector_type(4)));
typedef __bf16 bf16x8 __attribute__((ext_vector_type(8)));
typedef _Float16 f16;
typedef _Float16 f16x2 __attribute__((ext_vector_type(2)));
typedef _Float16 f16x4 __attribute__((ext_vector_type(4)));
typedef _Float16 f16x8 __attribute__((ext_vector_type(8)));
typedef __fp16 h16x2 __attribute__((ext_vector_type(2)));
typedef float f32x4 __attribute__((ext_vector_type(4)));
typedef float f32x16 __attribute__((ext_vector_type(16)));

#define D_MODEL 768
#define NUM_HEADS 48
#define HEAD_CH 16
#define INNER 2304
#define BATCH 2
#define SEQLEN 2048
#define M_ROWS (BATCH * SEQLEN)
#define EPSF 1e-6f
// S-tile stride (f16 elems). Must be 0 mod 8 (16B alignment of ds_read_b128).
#define SST 40
// h shift-replica table: hr_s[j] = h_ext[2048 + s - j], s in 0..3, j in [0,2084).
// Lane uses replica s = l31&3; per (g) one aligned ds_read_b64 yields
// elems r=0..3 = h_ext[E0 - r], E0 = (l0-mc) + l31 - 4*hi - 8*g.
#define HREP_LEN 2084
#define HREPQ (NUM_HEADS * 4 * (HREP_LEN / 4))  // f16x4 quads total

// cvt_pkrtz returns __fp16 vec2; bit-cast to _Float16 vec2
__device__ inline f16x2 pkrtz(float a, float b) {
  h16x2 r = __builtin_amdgcn_cvt_pkrtz(a, b);
  union { h16x2 i; f16x2 o; } u;
  u.i = r;
  return u.o;
}

// async global->LDS, 16B per lane. LDS dest must be wave-uniform base + lane*16.
__device__ inline void gload_lds16(const void* g, void* l) {
  __builtin_amdgcn_global_load_lds((__attribute__((address_space(1))) void*)(g),
                                   (__attribute__((address_space(3))) void*)(l),
                                   16, 0, 0);
}

// ---------------------------------------------------------------------------
// fused dual f32 -> bf16 convert (two independent tensors, one launch)
// ---------------------------------------------------------------------------
__global__ __launch_bounds__(256) void cvt2_f32_bf16(
    const float* __restrict__ a, bf16* __restrict__ da, int na4,
    const float* __restrict__ b, bf16* __restrict__ db, int nb4) {
  int j = blockIdx.x * 256 + threadIdx.x;
  const float* s;
  bf16* d;
  if (j < na4) {
    s = a; d = da;
  } else {
    j -= na4;
    if (j >= nb4) return;
    s = b; d = db;
  }
  const float4 v = ((const float4*)s)[j];
  bf16x4 o;
  o[0] = (bf16)v.x; o[1] = (bf16)v.y; o[2] = (bf16)v.z; o[3] = (bf16)v.w;
  ((bf16x4*)d)[j] = o;
}

// ---------------------------------------------------------------------------
// w_out f32->bf16 convert + h shift-replica table gen (runs after conv so the
// dead u-region tail can hold the table). hrep layout [nh][s][HREP_LEN] f16.
// ---------------------------------------------------------------------------
__global__ __launch_bounds__(256) void cvt_wout_hgen(
    const float* __restrict__ wout, bf16* __restrict__ wout16, int n4,
    const float* __restrict__ hb, f16* __restrict__ hrep) {
  int j = blockIdx.x * 256 + threadIdx.x;
  if (j < n4) {
    const float4 v = ((const float4*)wout)[j];
    bf16x4 o;
    o[0] = (bf16)v.x; o[1] = (bf16)v.y; o[2] = (bf16)v.z; o[3] = (bf16)v.w;
    ((bf16x4*)wout16)[j] = o;
    return;
  }
  j -= n4;
  if (j >= HREPQ) return;
  const int nh = j / (HREP_LEN);        // 4 * 521 quads per head
  const int rem = j - nh * HREP_LEN;
  const int s = rem / (HREP_LEN / 4), j4 = rem - s * (HREP_LEN / 4);
  const float* hrow = hb + nh * SEQLEN;
  f16x4 o;
#pragma unroll
  for (int rr = 0; rr < 4; ++rr) {
    const int jj = 4 * j4 + rr;
    const int i = 2048 + s - jj;
    o[rr] = (f16)((i >= 0 && i < 2048) ? hrow[i] : 0.f);
  }
  ((f16x4*)hrep)[j] = o;
}

// ---------------------------------------------------------------------------
// GEMM: C[m,n] = sum_k A[m,k]*W[n,k] + bias[n] (+ skip[m,n]); A (M,K), W (N,K)
// m97 pattern, TM x TN tile, BK=64.
// ---------------------------------------------------------------------------
template <int TM, int TN, int BK, int NCOLS, bool ADD_SKIP, typename CT>
__global__ __launch_bounds__(256) void gemm_bt(
    const bf16* __restrict__ A, const bf16* __restrict__ W,
    const float* __restrict__ bias, const float* __restrict__ skip,
    CT* __restrict__ C, int K) {
  constexpr int MI = TM / 32;  // m-frags per wave
  constexpr int NI = TN / 32;  // n-frags per wave
  constexpr int KK = BK / 32;  // k sub-blocks
  __shared__ __align__(16) bf16 As[TM * BK];
  __shared__ __align__(16) bf16 Bs[TN * BK];
  const int t = threadIdx.x;
  const int lane = t & 63, w = t >> 6;
  const int wm = (w >> 1) * (TM / 2), wn = (w & 1) * (TN / 2);
  const int row16 = lane & 15, quad = lane >> 4;
  const int m0 = blockIdx.x * TM, n0 = blockIdx.y * TN;

  f32x4 zero4 = {0.f, 0.f, 0.f, 0.f};
  f32x4 acc[MI][NI];
#pragma unroll
  for (int mi = 0; mi < MI; ++mi)
#pragma unroll
    for (int ni = 0; ni < NI; ++ni) acc[mi][ni] = zero4;

  const int arow = t >> 2;        // 0..63
  const int acol = (t & 3) * 8;   // 0..24
  const bf16* Ab = A + (size_t)m0 * K;
  const bf16* Wb = W + (size_t)n0 * K;

  for (int kt = 0; kt < K; kt += BK) {
#pragma unroll
    for (int kk0 = 0; kk0 < KK; ++kk0) {
#pragma unroll
      for (int rh = 0; rh < TM / 64; ++rh)
        gload_lds16(Ab + (size_t)(rh * 64 + arow) * K + kt + kk0 * 32 + acol,
                    As + kk0 * (TM * 32) + rh * 2048 + t * 8);
#pragma unroll
      for (int rh = 0; rh < TN / 64; ++rh)
        gload_lds16(Wb + (size_t)(rh * 64 + arow) * K + kt + kk0 * 32 + acol,
                    Bs + kk0 * (TN * 32) + rh * 2048 + t * 8);
    }
    __syncthreads();

    bf16x8 af[MI][KK], wf[NI][KK];
#pragma unroll
    for (int kk0 = 0; kk0 < KK; ++kk0) {
#pragma unroll
      for (int mi = 0; mi < MI; ++mi)
        af[mi][kk0] = *(const bf16x8*)&As[kk0 * (TM * 32) +
                                          (wm + mi * 16 + row16) * 32 +
                                          quad * 8];
#pragma unroll
      for (int ni = 0; ni < NI; ++ni)
        wf[ni][kk0] = *(const bf16x8*)&Bs[kk0 * (TN * 32) +
                                          (wn + ni * 16 + row16) * 32 +
                                          quad * 8];
    }
#pragma unroll
    for (int kk0 = 0; kk0 < KK; ++kk0)
#pragma unroll
      for (int mi = 0; mi < MI; ++mi)
#pragma unroll
        for (int ni = 0; ni < NI; ++ni)
          acc[mi][ni] = __builtin_amdgcn_mfma_f32_16x16x32_bf16(
              af[mi][kk0], wf[ni][kk0], acc[mi][ni], 0, 0, 0);
    __syncthreads();
  }

#pragma unroll
  for (int mi = 0; mi < MI; ++mi) {
#pragma unroll
    for (int ni = 0; ni < NI; ++ni) {
      const int col = n0 + wn + ni * 16 + row16;
      const float bv = bias[col];
#pragma unroll
      for (int r = 0; r < 4; ++r) {
        const int row = m0 + wm + mi * 16 + quad * 4 + r;
        float v = acc[mi][ni][r] + bv;
        if (ADD_SKIP) v += skip[(size_t)row * NCOLS + col];
        C[(size_t)row * NCOLS + col] = (CT)v;
      }
    }
  }
}

// ---------------------------------------------------------------------------
// Q+K+V causal width-3 conv from u (all outputs f16 now):
//   ch 0..15  -> Q (B,N,L,16);  16..31 -> K (B,N,L,16);  32..47 -> V (B,N,16,L)
// ---------------------------------------------------------------------------
__global__ __launch_bounds__(256) void conv_qkv(
    const bf16* __restrict__ u, const float* __restrict__ w_sf,
    const float* __restrict__ b_sf, f16* __restrict__ qq,
    f16* __restrict__ kk, f16* __restrict__ vv) {
  const int nh = blockIdx.x, b = blockIdx.y, lc = blockIdx.z;
  const int l0 = lc * 128;
  __shared__ __align__(8) bf16 ut[130 * 48];
  const int t = threadIdx.x;
  for (int i = t; i < 130 * 12; i += 256) {
    const int lr = i / 12, qd = i % 12;
    const int l = l0 - 2 + lr;
    uint2 val;
    val.x = 0u; val.y = 0u;
    if (l >= 0)
      val = *(const uint2*)&u[(size_t)(b * SEQLEN + l) * INNER + nh * 48 + qd * 4];
    *(uint2*)&ut[lr * 48 + qd * 4] = val;
  }
  __syncthreads();
  const size_t bn = (size_t)(b * NUM_HEADS + nh);
#pragma unroll
  for (int s = 0; s < 2; ++s) {
    f16* dst = (s == 0) ? qq : kk;
    const int cb = s * 16;
    for (int i = t; i < 128 * 16; i += 256) {
      const int c = i & 15, lr = i >> 4;
      const int e = nh * 48 + cb + c;
      const float val = w_sf[e * 3 + 0] * (float)ut[lr * 48 + cb + c] +
                        w_sf[e * 3 + 1] * (float)ut[(lr + 1) * 48 + cb + c] +
                        w_sf[e * 3 + 2] * (float)ut[(lr + 2) * 48 + cb + c] +
                        b_sf[e];
      dst[(bn * SEQLEN + l0 + lr) * 16 + c] = (f16)val;
    }
  }
  for (int i = t; i < 128 * 16; i += 256) {
    const int lr = i & 127, c = i >> 7;
    const int e = nh * 48 + 32 + c;
    const float val = w_sf[e * 3 + 0] * (float)ut[lr * 48 + 32 + c] +
                      w_sf[e * 3 + 1] * (float)ut[(lr + 1) * 48 + 32 + c] +
                      w_sf[e * 3 + 2] * (float)ut[(lr + 2) * 48 + 32 + c] +
                      b_sf[e];
    vv[(bn * 16 + c) * SEQLEN + l0 + lr] = (f16)val;
  }
}

// ---------------------------------------------------------------------------
// Causal h-weighted attention v12: merged paired-tile loop, f16 pipeline.
// Block z owns tiles (z, 63-z). Each wave runs its A-chunk and B-chunk chain
// per iteration (independent S-buffers/accums/prefetch) -> 2x ILP, one shared
// lgkmcnt sync. h via 4 shifted f16 replicas in LDS: 4x ds_read_b64 replaces
// 16x ds_read_b32. S->P: cvt_pkrtz + v_pk_mul_f16 (8+8 packed ops).
// ---------------------------------------------------------------------------
__global__ __launch_bounds__(256) void attn_kernel(
    const f16* __restrict__ qq, const f16* __restrict__ kk,
    const f16* __restrict__ vv, const f16* __restrict__ hrep,
    bf16* __restrict__ y) {
  const int nh = blockIdx.x, b = blockIdx.y;
  const int qa = blockIdx.z, qb = 63 - qa;  // paired tiles
  const int l0a = qa * 32, l0b = qb * 32;
  __shared__ __align__(16) f16 hr[4 * HREP_LEN];   // 16,672 B
  __shared__ __align__(16) f16 st[8 * 32 * SST];   // 20,480 B (2 bufs/wave)
  const int t = threadIdx.x;
  {  // stage this head's 4 h-replicas into LDS (coalesced 16B copies)
    const uint4* src = (const uint4*)(hrep + (size_t)nh * 4 * HREP_LEN);
    uint4* dst = (uint4*)hr;
    for (int i = t; i < 4 * HREP_LEN / 8; i += 256) dst[i] = src[i];
  }
  __syncthreads();

  const int w = t >> 6, lane = t & 63;
  const int l31 = lane & 31, hi = lane >> 5;
  const int row16 = lane & 15, quad = lane >> 4;
  const size_t bn = (size_t)(b * NUM_HEADS + nh);
  const f16* qp = qq + bn * SEQLEN * 16;
  const f16* kb = kk + bn * SEQLEN * 16;
  const f16* vrp = vv + (bn * 16 + row16) * SEQLEN;
  // per-lane replica pointer + base index: j0(g) = jbase - (l0-mc) + 8g
  const f16* hlp = &hr[(l31 & 3) * HREP_LEN];
  const int jbase = 2048 + (l31 & 3) - l31 + 4 * hi;

  f16x8 zf;
#pragma unroll
  for (int j = 0; j < 8; ++j) zf[j] = (f16)0.f;
  const f32x4 z4 = {0.f, 0.f, 0.f, 0.f};
  f32x16 zacc;
#pragma unroll
  for (int j = 0; j < 16; ++j) zacc[j] = 0.f;

  const f16x8 qfa = *(const f16x8*)&qp[(l0a + l31) * 16 + hi * 8];
  const f16x8 qfb = *(const f16x8*)&qp[(l0b + l31) * 16 + hi * 8];

  auto ldk = [&](int mc) { return *(const f16x8*)&kb[(mc + l31) * 16 + hi * 8]; };
  auto ldv = [&](int mc) { return *(const f16x8*)&vrp[mc + quad * 8]; };

  // weight S (f32x16, S^T layout: lane=col l31, reg 4g+r -> m=4hi+8g+r) by
  // h_ext[(l0-mc)+l-m] and store f16 P-tile row l31 to sw.
  auto wstore = [&](const f32x16& s, const int delta, f16* sw) {
    const int jb = jbase - delta;
#pragma unroll
    for (int g = 0; g < 4; ++g) {
      const f16x4 hv = *(const f16x4*)&hlp[jb + 8 * g];
      f16x2 p0 = pkrtz(s[4 * g + 0], s[4 * g + 1]);
      f16x2 p1 = pkrtz(s[4 * g + 2], s[4 * g + 3]);
      f16x2 h0; h0[0] = hv[0]; h0[1] = hv[1];
      f16x2 h1; h1[0] = hv[2]; h1[1] = hv[3];
      p0 *= h0;
      p1 *= h1;
      f16x4 pw;
      pw[0] = p0[0]; pw[1] = p0[1]; pw[2] = p1[0]; pw[3] = p1[1];
      *(f16x4*)&sw[l31 * SST + 8 * g + 4 * hi] = pw;
    }
  };
  auto pv = [&](const f16* sw, const f16x8 vf, f32x4& o0, f32x4& o1) {
    const f16x8 sf0 = *(const f16x8*)&sw[row16 * SST + quad * 8];
    const f16x8 sf1 = *(const f16x8*)&sw[(row16 + 16) * SST + quad * 8];
    o0 = __builtin_amdgcn_mfma_f32_16x16x32_f16(sf0, vf, o0, 0, 0, 0);
    o1 = __builtin_amdgcn_mfma_f32_16x16x32_f16(sf1, vf, o1, 0, 0, 0);
  };

  int mcA = w * 32;
  const int j0r = ((w - qa - 1) % 4 + 4) % 4;  // balance nB across waves
  int mcB = j0r * 32;
  f16x8 kfA = zf, vfA = zf, kfB = zf, vfB = zf;
  if (mcA <= l0a) { kfA = ldk(mcA); vfA = ldv(mcA); }
  if (mcB <= l0b) { kfB = ldk(mcB); vfB = ldv(mcB); }
  f16* swA = st + (size_t)(2 * w + 0) * 32 * SST;
  f16* swB = st + (size_t)(2 * w + 1) * 32 * SST;
  f32x4 o0a = z4, o1a = z4, o0b = z4, o1b = z4;

  while ((mcA <= l0a) || (mcB <= l0b)) {
    const bool aA = (mcA <= l0a), aB = (mcB <= l0b);
    f16x8 kfA2 = zf, vfA2 = zf, kfB2 = zf, vfB2 = zf;
    if (mcA + 128 <= l0a) { kfA2 = ldk(mcA + 128); vfA2 = ldv(mcA + 128); }
    if (mcB + 128 <= l0b) { kfB2 = ldk(mcB + 128); vfB2 = ldv(mcB + 128); }
    if (aA) {
      const f32x16 sA =
          __builtin_amdgcn_mfma_f32_32x32x16_f16(kfA, qfa, zacc, 0, 0, 0);
      wstore(sA, l0a - mcA, swA);
    }
    if (aB) {
      const f32x16 sB =
          __builtin_amdgcn_mfma_f32_32x32x16_f16(kfB, qfb, zacc, 0, 0, 0);
      wstore(sB, l0b - mcB, swB);
    }
    asm volatile("s_waitcnt lgkmcnt(0)" ::: "memory");  // stores -> reads
    if (aA) {
      pv(swA, vfA, o0a, o1a);
      kfA = kfA2; vfA = vfA2; mcA += 128;
    }
    if (aB) {
      pv(swB, vfB, o0b, o1b);
      kfB = kfB2; vfB = vfB2; mcB += 128;
    }
    asm volatile("" ::: "memory");  // reads before next-iter stores
  }

  // epilogue: two phases reusing st as 4 x (32x16 f32) reduction buffers
  float* ob = (float*)(st + (size_t)w * 2 * 32 * SST);
#pragma unroll
  for (int phase = 0; phase < 2; ++phase) {
    const f32x4& p0 = phase ? o0b : o0a;
    const f32x4& p1 = phase ? o1b : o1a;
    const int lt = phase ? l0b : l0a;
    if (phase) __syncthreads();
#pragma unroll
    for (int r = 0; r < 4; ++r) {
      ob[(quad * 4 + r) * 16 + row16] = p0[r];
      ob[(quad * 4 + r + 16) * 16 + row16] = p1[r];
    }
    __syncthreads();
    for (int i = t; i < 32 * 16; i += 256) {
      const int l = i >> 4, jj = i & 15;
      float sum = 0.f;
#pragma unroll
      for (int ww = 0; ww < 4; ++ww)
        sum += ((const float*)(st + (size_t)ww * 2 * 32 * SST))[l * 16 + jj];
      y[((size_t)(b * SEQLEN + lt + l) * NUM_HEADS + nh) * 16 + jj] = (bf16)sum;
    }
  }
}

// ---------------------------------------------------------------------------
// RMSNorm over D=768 per row: y bf16 in, yn bf16 out, * norm_w (f32)
// ---------------------------------------------------------------------------
__global__ __launch_bounds__(256) void rmsnorm_k(
    const bf16* __restrict__ y, const float* __restrict__ nw,
    bf16* __restrict__ yn) {
  const int row = blockIdx.x;
  const int t = threadIdx.x;
  const bf16* yr = y + (size_t)row * D_MODEL;
  const float v0 = (float)yr[t];
  const float v1 = (float)yr[t + 256];
  const float v2 = (float)yr[t + 512];
  float ss = v0 * v0 + v1 * v1 + v2 * v2;
#pragma unroll
  for (int off = 32; off >= 1; off >>= 1) ss += __shfl_down(ss, off, 64);
  __shared__ float red[4];
  if ((t & 63) == 0) red[t >> 6] = ss;
  __syncthreads();
  const float tot = red[0] + red[1] + red[2] + red[3];
  const float r = rsqrtf(tot * (1.f / 768.f) + EPSF);
  bf16* yo = yn + (size_t)row * D_MODEL;
  yo[t] = (bf16)(v0 * r * nw[t]);
  yo[t + 256] = (bf16)(v1 * r * nw[t + 256]);
  yo[t + 512] = (bf16)(v2 * r * nw[t + 512]);
}

// ---------------------------------------------------------------------------
extern "C" void kernel_launch(void* const* d_in, const int* in_sizes, int n_in,
                              void* d_out, int out_size, void* d_ws,
                              size_t ws_size, hipStream_t stream) {
  const float* inputs = (const float*)d_in[0];
  const float* w_in = (const float*)d_in[1];
  const float* b_in = (const float*)d_in[2];
  const float* w_sf = (const float*)d_in[3];
  const float* b_sf = (const float*)d_in[4];
  const float* hb = (const float*)d_in[5];
  const float* norm_w = (const float*)d_in[6];
  const float* w_out = (const float*)d_in[7];
  const float* b_out = (const float*)d_in[8];

  // ws plan (37.8 MB), region lifetimes:
  //   u   18 MiB : GEMM1 out -> dead after conv_qkv; tail reused for
  //                wout16 (+0, 1.2MB), yn (+2MiB, 6MiB), y16 (+8MiB, 6MiB),
  //                hrep (+14MiB, 0.8MB h replica table)
  //   v    6.3 MB : V (f16)
  //   A    6.3 MB : in16 (GEMM1 A) -> k16 (attn) -> dead
  //   B    6.3 MB : win16 (GEMM1 W, 3.5MB) -> q16 (attn)
  char* ws = (char*)d_ws;
  const size_t U_B = (size_t)M_ROWS * INNER * 2;
  const size_t V_B = (size_t)BATCH * NUM_HEADS * HEAD_CH * SEQLEN * 2;
  const size_t SLOT_B = (size_t)M_ROWS * D_MODEL * 2;
  bf16* u = (bf16*)(ws);
  bf16* wout16 = (bf16*)(ws);                    // u region, after conv
  bf16* yn = (bf16*)(ws + (2 << 20));            // u region +2MiB
  bf16* y16 = (bf16*)(ws + (8 << 20));           // u region +8MiB (..14MiB)
  f16* hrep = (f16*)(ws + (14 << 20));           // u region +14MiB (..14.8MiB)
  f16* v = (f16*)(ws + U_B);
  bf16* in16 = (bf16*)(ws + U_B + V_B);          // A
  f16* k16 = (f16*)in16;                         // A after GEMM1
  bf16* win16 = (bf16*)(ws + U_B + V_B + SLOT_B);// B
  f16* q16 = (f16*)win16;                        // B after GEMM1
  float* out = (float*)d_out;

  const int n4_in = M_ROWS * D_MODEL / 4;
  const int n4_win = INNER * D_MODEL / 4;
  const int n4_wout = D_MODEL * D_MODEL / 4;
  hipLaunchKernelGGL(cvt2_f32_bf16, dim3((n4_in + n4_win + 255) / 256),
                     dim3(256), 0, stream, inputs, in16, n4_in, w_in, win16,
                     n4_win);

  hipLaunchKernelGGL((gemm_bt<64, 128, 64, INNER, false, bf16>), dim3(64, 18),
                     dim3(256), 0, stream, in16, win16, b_in,
                     (const float*)nullptr, u, 768);
  hipLaunchKernelGGL(conv_qkv, dim3(48, 2, 16), dim3(256), 0, stream, u, w_sf,
                     b_sf, q16, k16, v);
  // u dead now: stage w_out + h replica table into its head/tail
  hipLaunchKernelGGL(cvt_wout_hgen, dim3((n4_wout + HREPQ + 255) / 256),
                     dim3(256), 0, stream, w_out, wout16, n4_wout, hb, hrep);
  hipLaunchKernelGGL(attn_kernel, dim3(48, 2, 32), dim3(256), 0, stream, q16,
                     k16, v, hrep, y16);
  hipLaunchKernelGGL(rmsnorm_k, dim3(M_ROWS), dim3(256), 0, stream, y16,
                     norm_w, yn);
  hipLaunchKernelGGL((gemm_bt<64, 64, 64, D_MODEL, true, float>), dim3(64, 12),
                     dim3(256), 0, stream, yn, wout16, b_out, inputs, out,
                     768);
}

// Round 5
// 185.306 us; speedup vs baseline: 1.1533x; 1.0573x over previous
//
#include <hip/hip_runtime.h>
#include <hip/hip_bf16.h>
#include <stdint.h>

typedef __bf16 bf16;
typedef __bf16 bf16x4 __attribute__((ext_vector_type(4)));
typedef __bf16 bf16x8 __attribute__((ext_vector_type(8)));
typedef float f32x4 __attribute__((ext_vector_type(4)));
typedef float f32x16 __attribute__((ext_vector_type(16)));

#define D_MODEL 768
#define NUM_HEADS 48
#define HEAD_CH 16
#define INNER 2304
#define BATCH 2
#define SEQLEN 2048
#define M_ROWS (BATCH * SEQLEN)
#define EPSF 1e-6f
// S-tile stride (bf16). MUST be 0 mod 8 (16B row alignment for ds_read_b128).
#define SST 40

// async global->LDS, 16B per lane. LDS dest must be wave-uniform base + lane*16.
__device__ inline void gload_lds16(const void* g, void* l) {
  __builtin_amdgcn_global_load_lds((__attribute__((address_space(1))) void*)(g),
                                   (__attribute__((address_space(3))) void*)(l),
                                   16, 0, 0);
}

// ---------------------------------------------------------------------------
// fused dual f32 -> bf16 convert (two independent tensors, one launch)
// ---------------------------------------------------------------------------
__global__ __launch_bounds__(256) void cvt2_f32_bf16(
    const float* __restrict__ a, bf16* __restrict__ da, int na4,
    const float* __restrict__ b, bf16* __restrict__ db, int nb4) {
  int j = blockIdx.x * 256 + threadIdx.x;
  const float* s;
  bf16* d;
  if (j < na4) {
    s = a; d = da;
  } else {
    j -= na4;
    if (j >= nb4) return;
    s = b; d = db;
  }
  const float4 v = ((const float4*)s)[j];
  bf16x4 o;
  o[0] = (bf16)v.x; o[1] = (bf16)v.y; o[2] = (bf16)v.z; o[3] = (bf16)v.w;
  ((bf16x4*)d)[j] = o;
}

__global__ __launch_bounds__(256) void cvt_f32_bf16(
    const float* __restrict__ src, bf16* __restrict__ dst, int n4) {
  const int i = blockIdx.x * 256 + threadIdx.x;
  if (i < n4) {
    const float4 v = ((const float4*)src)[i];
    bf16x4 o;
    o[0] = (bf16)v.x; o[1] = (bf16)v.y; o[2] = (bf16)v.z; o[3] = (bf16)v.w;
    ((bf16x4*)dst)[i] = o;
  }
}

// ---------------------------------------------------------------------------
// GEMM: C[m,n] = sum_k A[m,k]*W[n,k] + bias[n] (+ skip[m,n]); A (M,K), W (N,K)
// m97 pattern, TM x TN tile, BK=64: two [kk0][row][32] sub-blocks -> DMA
// contiguity + 32-col fragment addressing preserved, 12 iters at K=768.
// gemm1 now 128x128 (m97 geometry: 2x2 waves of 64x64) — measured ladder puts
// 64-class tiles at ~343-517 TF vs 874-912 TF at 128^2.
// ---------------------------------------------------------------------------
template <int TM, int TN, int BK, int NCOLS, bool ADD_SKIP, typename CT>
__global__ __launch_bounds__(256) void gemm_bt(
    const bf16* __restrict__ A, const bf16* __restrict__ W,
    const float* __restrict__ bias, const float* __restrict__ skip,
    CT* __restrict__ C, int K) {
  constexpr int MI = TM / 32;  // m-frags per wave
  constexpr int NI = TN / 32;  // n-frags per wave
  constexpr int KK = BK / 32;  // k sub-blocks
  __shared__ __align__(16) bf16 As[TM * BK];
  __shared__ __align__(16) bf16 Bs[TN * BK];
  const int t = threadIdx.x;
  const int lane = t & 63, w = t >> 6;
  const int wm = (w >> 1) * (TM / 2), wn = (w & 1) * (TN / 2);
  const int row16 = lane & 15, quad = lane >> 4;
  const int m0 = blockIdx.x * TM, n0 = blockIdx.y * TN;

  f32x4 zero4 = {0.f, 0.f, 0.f, 0.f};
  f32x4 acc[MI][NI];
#pragma unroll
  for (int mi = 0; mi < MI; ++mi)
#pragma unroll
    for (int ni = 0; ni < NI; ++ni) acc[mi][ni] = zero4;

  const int arow = t >> 2;        // 0..63
  const int acol = (t & 3) * 8;   // 0..24
  const bf16* Ab = A + (size_t)m0 * K;
  const bf16* Wb = W + (size_t)n0 * K;

  for (int kt = 0; kt < K; kt += BK) {
#pragma unroll
    for (int kk0 = 0; kk0 < KK; ++kk0) {
#pragma unroll
      for (int rh = 0; rh < TM / 64; ++rh)
        gload_lds16(Ab + (size_t)(rh * 64 + arow) * K + kt + kk0 * 32 + acol,
                    As + kk0 * (TM * 32) + rh * 2048 + t * 8);
#pragma unroll
      for (int rh = 0; rh < TN / 64; ++rh)
        gload_lds16(Wb + (size_t)(rh * 64 + arow) * K + kt + kk0 * 32 + acol,
                    Bs + kk0 * (TN * 32) + rh * 2048 + t * 8);
    }
    __syncthreads();

    bf16x8 af[MI][KK], wf[NI][KK];
#pragma unroll
    for (int kk0 = 0; kk0 < KK; ++kk0) {
#pragma unroll
      for (int mi = 0; mi < MI; ++mi)
        af[mi][kk0] = *(const bf16x8*)&As[kk0 * (TM * 32) +
                                          (wm + mi * 16 + row16) * 32 +
                                          quad * 8];
#pragma unroll
      for (int ni = 0; ni < NI; ++ni)
        wf[ni][kk0] = *(const bf16x8*)&Bs[kk0 * (TN * 32) +
                                          (wn + ni * 16 + row16) * 32 +
                                          quad * 8];
    }
#pragma unroll
    for (int kk0 = 0; kk0 < KK; ++kk0)
#pragma unroll
      for (int mi = 0; mi < MI; ++mi)
#pragma unroll
        for (int ni = 0; ni < NI; ++ni)
          acc[mi][ni] = __builtin_amdgcn_mfma_f32_16x16x32_bf16(
              af[mi][kk0], wf[ni][kk0], acc[mi][ni], 0, 0, 0);
    __syncthreads();
  }

#pragma unroll
  for (int mi = 0; mi < MI; ++mi) {
#pragma unroll
    for (int ni = 0; ni < NI; ++ni) {
      const int col = n0 + wn + ni * 16 + row16;
      const float bv = bias[col];
#pragma unroll
      for (int r = 0; r < 4; ++r) {
        const int row = m0 + wm + mi * 16 + quad * 4 + r;
        float v = acc[mi][ni][r] + bv;
        if (ADD_SKIP) v += skip[(size_t)row * NCOLS + col];
        C[(size_t)row * NCOLS + col] = (CT)v;
      }
    }
  }
}

// ---------------------------------------------------------------------------
// Q+K+V causal width-3 conv from u:
//   ch 0..15  -> Q (B,N,L,16);  16..31 -> K (B,N,L,16);  32..47 -> V (B,N,16,L)
// ---------------------------------------------------------------------------
__global__ __launch_bounds__(256) void conv_qkv(
    const bf16* __restrict__ u, const float* __restrict__ w_sf,
    const float* __restrict__ b_sf, bf16* __restrict__ qq,
    bf16* __restrict__ kk, bf16* __restrict__ vv) {
  const int nh = blockIdx.x, b = blockIdx.y, lc = blockIdx.z;
  const int l0 = lc * 128;
  __shared__ __align__(8) bf16 ut[130 * 48];
  const int t = threadIdx.x;
  for (int i = t; i < 130 * 12; i += 256) {
    const int lr = i / 12, qd = i % 12;
    const int l = l0 - 2 + lr;
    uint2 val;
    val.x = 0u; val.y = 0u;
    if (l >= 0)
      val = *(const uint2*)&u[(size_t)(b * SEQLEN + l) * INNER + nh * 48 + qd * 4];
    *(uint2*)&ut[lr * 48 + qd * 4] = val;
  }
  __syncthreads();
  const size_t bn = (size_t)(b * NUM_HEADS + nh);
#pragma unroll
  for (int s = 0; s < 2; ++s) {
    bf16* dst = (s == 0) ? qq : kk;
    const int cb = s * 16;
    for (int i = t; i < 128 * 16; i += 256) {
      const int c = i & 15, lr = i >> 4;
      const int e = nh * 48 + cb + c;
      const float val = w_sf[e * 3 + 0] * (float)ut[lr * 48 + cb + c] +
                        w_sf[e * 3 + 1] * (float)ut[(lr + 1) * 48 + cb + c] +
                        w_sf[e * 3 + 2] * (float)ut[(lr + 2) * 48 + cb + c] +
                        b_sf[e];
      dst[(bn * SEQLEN + l0 + lr) * 16 + c] = (bf16)val;
    }
  }
  for (int i = t; i < 128 * 16; i += 256) {
    const int lr = i & 127, c = i >> 7;
    const int e = nh * 48 + 32 + c;
    const float val = w_sf[e * 3 + 0] * (float)ut[lr * 48 + 32 + c] +
                      w_sf[e * 3 + 1] * (float)ut[(lr + 1) * 48 + 32 + c] +
                      w_sf[e * 3 + 2] * (float)ut[(lr + 2) * 48 + 32 + c] +
                      b_sf[e];
    vv[(bn * 16 + c) * SEQLEN + l0 + lr] = (bf16)val;
  }
}

// ---------------------------------------------------------------------------
// Causal h-weighted attention v10 (r13, frozen): balanced paired tiles.
// Block z owns tiles (z, 63-z); 65 combined KV chunks dealt round-robin to
// the 4 waves -> uniform duration. 3072 blocks. S^T = mfma_32x32x16(K,Q);
// zero-padded LDS h; S->A via LDS (stride 40); PV = 2x mfma_16x16x32.
// (r1 LDS-free and r3 merged/f16 rewrites both failed to beat this: the
// kernel is latency/issue-bound at its structure, not pipe-throughput-bound.)
// ---------------------------------------------------------------------------
__global__ __launch_bounds__(256) void attn_kernel(
    const bf16* __restrict__ qq, const bf16* __restrict__ kk,
    const bf16* __restrict__ vv, const float* __restrict__ hg,
    bf16* __restrict__ y) {
  const int nh = blockIdx.x, b = blockIdx.y;
  const int qa = blockIdx.z, qb = 63 - qa;  // paired tiles
  const int l0a = qa * 32, l0b = qb * 32;
  __shared__ __align__(16) float hs[32 + SEQLEN];  // hs[32+d]=h[d], pad=0
  __shared__ __align__(16) bf16 st[4 * 32 * SST];  // per-wave S-tile / O-redux
  const int t = threadIdx.x;
  const int n4 = (l0b + 64) >> 2;
  for (int i = t; i < n4; i += 256) {
    float4 val = {0.f, 0.f, 0.f, 0.f};
    if (i >= 8) val = ((const float4*)(hg + nh * SEQLEN))[i - 8];
    ((float4*)hs)[i] = val;
  }
  __syncthreads();

  const int w = t >> 6, lane = t & 63;
  const int l31 = lane & 31, hi = lane >> 5;
  const int row16 = lane & 15, quad = lane >> 4;
  const size_t bn = (size_t)(b * NUM_HEADS + nh);
  const bf16* qp = qq + bn * SEQLEN * 16;
  const bf16* kb = kk + bn * SEQLEN * 16;
  const bf16* vb = vv + bn * 16 * SEQLEN;

  bf16x8 zf;
#pragma unroll
  for (int j = 0; j < 8; ++j) zf[j] = (bf16)0.f;
  const f32x4 zacc4 = {0.f, 0.f, 0.f, 0.f};
  f32x16 zacc16;
#pragma unroll
  for (int j = 0; j < 16; ++j) zacc16[j] = 0.f;

  const bf16x8 qfa = *(const bf16x8*)&qp[(l0a + l31) * 16 + hi * 8];
  const bf16x8 qfb = *(const bf16x8*)&qp[(l0b + l31) * 16 + hi * 8];

  bf16* sw = &st[w * 32 * SST];

  auto run_pass = [&](const bf16x8& qf, const int l0, const int mc0,
                      f32x4& o0, f32x4& o1) {
    int mc = mc0;
    bf16x8 kf = zf, vf = zf;
    if (mc <= l0) {
      kf = *(const bf16x8*)&kb[(mc + l31) * 16 + hi * 8];
      vf = *(const bf16x8*)&vb[row16 * SEQLEN + mc + quad * 8];
    }
    for (; mc <= l0; mc += 128) {
      const int mn = mc + 128;
      bf16x8 kf2 = zf, vf2 = zf;
      if (mn <= l0) {  // prefetch next chunk
        kf2 = *(const bf16x8*)&kb[(mn + l31) * 16 + hi * 8];
        vf2 = *(const bf16x8*)&vb[row16 * SEQLEN + mn + quad * 8];
      }
      // S^T[m-local=rows][l-local=cols] = sum_ch K*Q
      f32x16 s =
          __builtin_amdgcn_mfma_f32_32x32x16_bf16(kf, qf, zacc16, 0, 0, 0);

      // h-weight; causal mask free via zero pad. reg j -> hp[3-j]
      const int d0 = 32 + (l0 - mc) + l31 - 4 * hi;
#pragma unroll
      for (int g = 0; g < 4; ++g) {
        const float* hp = &hs[d0 - 8 * g - 3];
        bf16x4 pk;
        pk[0] = (bf16)(s[4 * g + 0] * hp[3]);
        pk[1] = (bf16)(s[4 * g + 1] * hp[2]);
        pk[2] = (bf16)(s[4 * g + 2] * hp[1]);
        pk[3] = (bf16)(s[4 * g + 3] * hp[0]);
        *(bf16x4*)&sw[l31 * SST + 8 * g + 4 * hi] = pk;
      }
      asm volatile("s_waitcnt lgkmcnt(0)" ::: "memory");  // stores -> reads
      const bf16x8 sf0 = *(const bf16x8*)&sw[row16 * SST + quad * 8];
      const bf16x8 sf1 = *(const bf16x8*)&sw[(row16 + 16) * SST + quad * 8];
      o0 = __builtin_amdgcn_mfma_f32_16x16x32_bf16(sf0, vf, o0, 0, 0, 0);
      o1 = __builtin_amdgcn_mfma_f32_16x16x32_bf16(sf1, vf, o1, 0, 0, 0);
      asm volatile("" ::: "memory");  // reads before next-iter stores
      kf = kf2; vf = vf2;
    }
  };

  f32x4 o0a = zacc4, o1a = zacc4, o0b = zacc4, o1b = zacc4;
  run_pass(qfa, l0a, w * 32, o0a, o1a);
  const int j0 = ((w - qa - 1) % 4 + 4) % 4;
  run_pass(qfb, l0b, j0 * 32, o0b, o1b);

  // epilogue: two phases reusing st as 4 x (32x16 f32) reduction buffers
  float* ob = (float*)&st[w * 32 * SST];
#pragma unroll
  for (int phase = 0; phase < 2; ++phase) {
    const f32x4& p0 = phase ? o0b : o0a;
    const f32x4& p1 = phase ? o1b : o1a;
    const int lt = phase ? l0b : l0a;
    __syncthreads();
#pragma unroll
    for (int r = 0; r < 4; ++r) {
      ob[(quad * 4 + r) * 16 + row16] = p0[r];
      ob[(quad * 4 + r + 16) * 16 + row16] = p1[r];
    }
    __syncthreads();
    for (int i = t; i < 32 * 16; i += 256) {
      const int l = i >> 4, j = i & 15;
      float sum = 0.f;
#pragma unroll
      for (int ww = 0; ww < 4; ++ww)
        sum += ((const float*)&st[ww * 32 * SST])[l * 16 + j];
      y[((size_t)(b * SEQLEN + lt + l) * NUM_HEADS + nh) * 16 + j] = (bf16)sum;
    }
  }
}

// ---------------------------------------------------------------------------
// RMSNorm over D=768 per row: y bf16 in, yn bf16 out, * norm_w (f32)
// ---------------------------------------------------------------------------
__global__ __launch_bounds__(256) void rmsnorm_k(
    const bf16* __restrict__ y, const float* __restrict__ nw,
    bf16* __restrict__ yn) {
  const int row = blockIdx.x;
  const int t = threadIdx.x;
  const bf16* yr = y + (size_t)row * D_MODEL;
  const float v0 = (float)yr[t];
  const float v1 = (float)yr[t + 256];
  const float v2 = (float)yr[t + 512];
  float ss = v0 * v0 + v1 * v1 + v2 * v2;
#pragma unroll
  for (int off = 32; off >= 1; off >>= 1) ss += __shfl_down(ss, off, 64);
  __shared__ float red[4];
  if ((t & 63) == 0) red[t >> 6] = ss;
  __syncthreads();
  const float tot = red[0] + red[1] + red[2] + red[3];
  const float r = rsqrtf(tot * (1.f / 768.f) + EPSF);
  bf16* yo = yn + (size_t)row * D_MODEL;
  yo[t] = (bf16)(v0 * r * nw[t]);
  yo[t + 256] = (bf16)(v1 * r * nw[t + 256]);
  yo[t + 512] = (bf16)(v2 * r * nw[t + 512]);
}

// ---------------------------------------------------------------------------
extern "C" void kernel_launch(void* const* d_in, const int* in_sizes, int n_in,
                              void* d_out, int out_size, void* d_ws,
                              size_t ws_size, hipStream_t stream) {
  const float* inputs = (const float*)d_in[0];
  const float* w_in = (const float*)d_in[1];
  const float* b_in = (const float*)d_in[2];
  const float* w_sf = (const float*)d_in[3];
  const float* b_sf = (const float*)d_in[4];
  const float* hb = (const float*)d_in[5];
  const float* norm_w = (const float*)d_in[6];
  const float* w_out = (const float*)d_in[7];
  const float* b_out = (const float*)d_in[8];

  // ws plan (37.8 MB), region lifetimes:
  //   u   18.9 MB : GEMM1 out -> dead after conv_qkv; tail reused for
  //                 wout16 (+0, 1.2MB), yn (+2MB, 6.3MB), y16 (+9MB, 6.3MB)
  //   v    6.3 MB : V
  //   A    6.3 MB : in16 (GEMM1 A) -> k16 (attn) -> dead
  //   B    6.3 MB : win16 (GEMM1 W, 3.5MB) -> q16 (attn)
  char* ws = (char*)d_ws;
  const size_t U_B = (size_t)M_ROWS * INNER * 2;
  const size_t V_B = (size_t)BATCH * NUM_HEADS * HEAD_CH * SEQLEN * 2;
  const size_t SLOT_B = (size_t)M_ROWS * D_MODEL * 2;
  bf16* u = (bf16*)(ws);
  bf16* wout16 = (bf16*)(ws);                    // u region, after conv
  bf16* yn = (bf16*)(ws + (2 << 20));            // u region +2MB
  bf16* y16 = (bf16*)(ws + (9 << 20));           // u region +9MB
  bf16* v = (bf16*)(ws + U_B);
  bf16* in16 = (bf16*)(ws + U_B + V_B);          // A
  bf16* k16 = in16;                              // A after GEMM1
  bf16* win16 = (bf16*)(ws + U_B + V_B + SLOT_B);// B
  bf16* q16 = win16;                             // B after GEMM1
  float* out = (float*)d_out;

  const int n4_in = M_ROWS * D_MODEL / 4;
  const int n4_win = INNER * D_MODEL / 4;
  const int n4_wout = D_MODEL * D_MODEL / 4;
  hipLaunchKernelGGL(cvt2_f32_bf16, dim3((n4_in + n4_win + 255) / 256),
                     dim3(256), 0, stream, inputs, in16, n4_in, w_in, win16,
                     n4_win);

  // gemm1: 128x128 m97 geometry (was 64x128) — grid (4096/128, 2304/128)
  hipLaunchKernelGGL((gemm_bt<128, 128, 64, INNER, false, bf16>), dim3(32, 18),
                     dim3(256), 0, stream, in16, win16, b_in,
                     (const float*)nullptr, u, 768);
  hipLaunchKernelGGL(conv_qkv, dim3(48, 2, 16), dim3(256), 0, stream, u, w_sf,
                     b_sf, q16, k16, v);
  // u dead now: stage w_out into its head
  hipLaunchKernelGGL(cvt_f32_bf16, dim3((n4_wout + 255) / 256), dim3(256), 0,
                     stream, w_out, wout16, n4_wout);
  hipLaunchKernelGGL(attn_kernel, dim3(48, 2, 32), dim3(256), 0, stream, q16,
                     k16, v, hb, y16);
  hipLaunchKernelGGL(rmsnorm_k, dim3(M_ROWS), dim3(256), 0, stream, y16,
                     norm_w, yn);
  hipLaunchKernelGGL((gemm_bt<64, 64, 64, D_MODEL, true, float>), dim3(64, 12),
                     dim3(256), 0, stream, yn, wout16, b_out, inputs, out,
                     768);
}